// Round 1
// baseline (1008.693 us; speedup 1.0000x reference)
//
#include <hip/hip_runtime.h>

// GRU, T=4096, B=256, I=2, H=32, O=1.
// Key insight: reference output uses hs[:, -1, :] == batch row 255 only.
// GRU batch rows are independent -> compute ONLY batch element 255.
// Sequential recurrence on a single wave; FC epilogue as a parallel kernel.

#define TT 4096
#define BB 256

__device__ __forceinline__ float rl(float v, int l) {
    return __int_as_float(__builtin_amdgcn_readlane(__float_as_int(v), l));
}
__device__ __forceinline__ float fexp(float x) {           // e^x
    return __builtin_amdgcn_exp2f(x * 1.44269504088896340736f);
}
__device__ __forceinline__ float fsig(float x) {           // 1/(1+e^-x)
    return __builtin_amdgcn_rcpf(1.0f + fexp(-x));
}
__device__ __forceinline__ float ftanh(float x) {          // 1 - 2/(1+e^{2x})
    return 1.0f - 2.0f * __builtin_amdgcn_rcpf(1.0f + fexp(2.0f * x));
}

// One wave. Lane l owns gate-row l (r rows 0..31 on lanes 0..31, z rows 32..63
// on lanes 32..63) and n-row 64+(l&31). h is kept replicated wave-uniform
// (readlane broadcast -> SGPRs); lane j<32 also keeps its own element h[j].
__global__ __launch_bounds__(64, 1) void gru_seq(
    const float* __restrict__ x,
    const float* __restrict__ w_ih,
    const float* __restrict__ w_hh,
    const float* __restrict__ b_ih,
    const float* __restrict__ b_hh,
    float* __restrict__ hbuf)
{
    const int lane = threadIdx.x;
    const int low  = lane & 31;
    const int row0 = lane;        // r/z rows
    const int row1 = 64 + low;    // n rows (duplicated on both half-waves; harmless)

    float w0[32], w1[32];
#pragma unroll
    for (int j = 0; j < 32; ++j) w0[j] = w_hh[row0 * 32 + j];
#pragma unroll
    for (int j = 0; j < 32; ++j) w1[j] = w_hh[row1 * 32 + j];

    const float wi00 = w_ih[row0 * 2 + 0];
    const float wi01 = w_ih[row0 * 2 + 1];
    const float wi10 = w_ih[row1 * 2 + 0];
    const float wi11 = w_ih[row1 * 2 + 1];
    const float bias0 = b_ih[row0] + b_hh[row0];  // r/z: both biases inside sigmoid
    const float bi1   = b_ih[row1];               // n: b_ih outside r*(...), b_hh inside
    const float bh1   = b_hh[row1];

    float h_s[32];                 // wave-uniform replicated h (SGPR-resident)
#pragma unroll
    for (int j = 0; j < 32; ++j) h_s[j] = 0.0f;
    float h_el = 0.0f;             // lane j<32 holds h[j]

    // x[t, 255, 0:2] as float2: index t*256 + 255. Block of 64 steps per load,
    // prefetched one block ahead.
    const float2* xp = (const float2*)x;
    float2 xv = xp[(size_t)lane * 256 + 255];

    for (int tb = 0; tb < 64; ++tb) {
        float2 xv_next = xv;
        if (tb < 63) xv_next = xp[((size_t)(tb + 1) * 64 + lane) * 256 + 255];
        float* hout = hbuf + (size_t)tb * 64 * 32 + low;

#pragma unroll 4
        for (int i = 0; i < 64; ++i) {
            const float x0 = rl(xv.x, i);
            const float x1 = rl(xv.y, i);

            // r/z pre-activation and n's hidden dot, 4-way ILP chains
            float a  = fmaf(x1, wi01, fmaf(x0, wi00, bias0));
            float b  = 0.f, c = 0.f, d = 0.f;
            float h0 = bh1, h1 = 0.f, h2 = 0.f, h3 = 0.f;
            const float xn = fmaf(x1, wi11, fmaf(x0, wi10, bi1));
#pragma unroll
            for (int j = 0; j < 32; j += 4) {
                a  = fmaf(h_s[j + 0], w0[j + 0], a);
                b  = fmaf(h_s[j + 1], w0[j + 1], b);
                c  = fmaf(h_s[j + 2], w0[j + 2], c);
                d  = fmaf(h_s[j + 3], w0[j + 3], d);
                h0 = fmaf(h_s[j + 0], w1[j + 0], h0);
                h1 = fmaf(h_s[j + 1], w1[j + 1], h1);
                h2 = fmaf(h_s[j + 2], w1[j + 2], h2);
                h3 = fmaf(h_s[j + 3], w1[j + 3], h3);
            }
            const float pre0 = (a + b) + (c + d);
            const float hn   = (h0 + h1) + (h2 + h3);

            const float sg = fsig(pre0);           // r on lanes<32, z on lanes>=32
            const float zv = __shfl_xor(sg, 32);   // z_j arrives at lane j (<32)
            const float nv = ftanh(fmaf(sg, hn, xn));  // n = tanh(xn + r*hn)

            // h_new = (1-z)*n + z*h = n + z*(h-n)
            h_el = fmaf(zv, h_el - nv, nv);

            if (lane < 32) hout[i * 32] = h_el;    // hbuf[t*32 + j]

            // broadcast new h to wave-uniform copy
#pragma unroll
            for (int j = 0; j < 32; ++j) h_s[j] = rl(h_el, j);
        }
        xv = xv_next;
    }
}

// out[t] = hbuf[t,:] . w_fc + b_fc
__global__ void fc_out(const float* __restrict__ hbuf,
                       const float* __restrict__ w_fc,
                       const float* __restrict__ b_fc,
                       float* __restrict__ out)
{
    const int t = blockIdx.x * blockDim.x + threadIdx.x;
    if (t >= TT) return;
    const float* h = hbuf + (size_t)t * 32;
    float acc = 0.f;
#pragma unroll
    for (int j = 0; j < 32; ++j) acc = fmaf(h[j], w_fc[j], acc);
    out[t] = acc + b_fc[0];
}

extern "C" void kernel_launch(void* const* d_in, const int* in_sizes, int n_in,
                              void* d_out, int out_size, void* d_ws, size_t ws_size,
                              hipStream_t stream) {
    const float* x    = (const float*)d_in[0];
    const float* w_ih = (const float*)d_in[1];
    const float* w_hh = (const float*)d_in[2];
    const float* b_ih = (const float*)d_in[3];
    const float* b_hh = (const float*)d_in[4];
    const float* w_fc = (const float*)d_in[5];
    const float* b_fc = (const float*)d_in[6];
    float* out  = (float*)d_out;
    float* hbuf = (float*)d_ws;   // TT*32*4 = 512 KB

    gru_seq<<<1, 64, 0, stream>>>(x, w_ih, w_hh, b_ih, b_hh, hbuf);
    fc_out<<<TT / 256, 256, 0, stream>>>(hbuf, w_fc, b_fc, out);
}

// Round 2
// 867.405 us; speedup vs baseline: 1.1629x; 1.1629x over previous
//
#include <hip/hip_runtime.h>

// GRU, T=4096, B=256, I=2, H=32, O=1.
// Only batch row 255 reaches the output -> compute only that row.
// Single-wave sequential recurrence; latency/issue-bound.
// R2: LDS-broadcast h (8x ds_read_b128) instead of 32 readlanes;
//     packed fp32 (v_pk_fma_f32) dots; both half-waves hold valid h.

#define TT 4096

typedef float v2f __attribute__((ext_vector_type(2)));

__device__ __forceinline__ v2f fma2(v2f a, v2f b, v2f c) {
    return __builtin_elementwise_fma(a, b, c);
}
__device__ __forceinline__ float rl(float v, int l) {
    return __int_as_float(__builtin_amdgcn_readlane(__float_as_int(v), l));
}
__device__ __forceinline__ float fexp2(float x) { return __builtin_amdgcn_exp2f(x); }
__device__ __forceinline__ float frcp(float x)  { return __builtin_amdgcn_rcpf(x); }
__device__ __forceinline__ float fsig(float x) {          // 1/(1+e^-x)
    return frcp(1.0f + fexp2(x * -1.44269504088896340736f));
}
__device__ __forceinline__ float ftanh(float x) {         // 1 - 2/(1+e^{2x})
    return fmaf(-2.0f, frcp(1.0f + fexp2(x * 2.88539008177792681472f)), 1.0f);
}

// One wave. Lane l owns gate-row l of w_hh[0:64] (r rows on lanes 0..31,
// z rows on lanes 32..63) and n-row 64+(l&31) (duplicated across halves).
// h lives in LDS[0..63]; every lane reads all 32 h values via broadcast
// ds_read_b128. After the r/z sigmoid, one shfl_xor(32) swaps r<->z so BOTH
// halves compute the same h_new bitwise (stores need no exec mask).
__global__ __launch_bounds__(64, 1) void gru_seq(
    const float* __restrict__ x,
    const float* __restrict__ w_ih,
    const float* __restrict__ w_hh,
    const float* __restrict__ b_ih,
    const float* __restrict__ b_hh,
    float* __restrict__ hbuf)
{
    __shared__ float hsm[64];

    const int lane = threadIdx.x;
    const int low  = lane & 31;
    const int row0 = lane;        // r/z row
    const int row1 = 64 + low;    // n row (both halves)
    const bool lo_half = lane < 32;

    // w_hh rows as float2 pairs (register-resident)
    const v2f* w_hh2 = (const v2f*)w_hh;
    v2f w0[16], w1[16];
#pragma unroll
    for (int k = 0; k < 16; ++k) w0[k] = w_hh2[row0 * 16 + k];
#pragma unroll
    for (int k = 0; k < 16; ++k) w1[k] = w_hh2[row1 * 16 + k];

    const float wi00 = w_ih[row0 * 2 + 0];
    const float wi01 = w_ih[row0 * 2 + 1];
    const float wi10 = w_ih[row1 * 2 + 0];
    const float wi11 = w_ih[row1 * 2 + 1];
    const float bias0 = b_ih[row0] + b_hh[row0];  // r/z: both biases inside sigmoid
    const float bi1   = b_ih[row1];               // n: b_ih outside r*(...)
    const float bh1   = b_hh[row1];               // n: b_hh inside r*(...)

    hsm[lane] = 0.0f;          // single wave: DS pipe is in-order, no barrier
    float h_el = 0.0f;         // each lane's copy of h[low]

    // x[t, 255, 0:2] as float2 at index t*256+255; one block of 64 steps per
    // lane-load, prefetched one block ahead.
    const float2* xp = (const float2*)x;
    float2 xv = xp[(size_t)lane * 256 + 255];

    const float4* h4 = (const float4*)hsm;

    for (int tb = 0; tb < 64; ++tb) {
        float2 xv_next = xv;
        if (tb < 63) xv_next = xp[((size_t)(tb + 1) * 64 + lane) * 256 + 255];
        float* hout = hbuf + (size_t)tb * 64 * 32 + low;

        for (int i = 0; i < 64; ++i) {
            const float x0 = rl(xv.x, i);
            const float x1 = rl(xv.y, i);
            const float base0 = fmaf(x1, wi01, fmaf(x0, wi00, bias0));
            const float xn    = fmaf(x1, wi11, fmaf(x0, wi10, bi1));

            // broadcast-read h: 8 x ds_read_b128, all lanes same address
            float4 hq[8];
#pragma unroll
            for (int k = 0; k < 8; ++k) hq[k] = h4[k];

            // packed dots: rz-row (per-lane) and n-row, 2 pk chains each
            v2f arz0 = {base0, 0.0f}, arz1 = {0.0f, 0.0f};
            v2f an0  = {bh1,   0.0f}, an1  = {0.0f, 0.0f};
#pragma unroll
            for (int k = 0; k < 8; ++k) {
                v2f hl = {hq[k].x, hq[k].y};
                v2f hh = {hq[k].z, hq[k].w};
                arz0 = fma2(hl, w0[2 * k],     arz0);
                arz1 = fma2(hh, w0[2 * k + 1], arz1);
                an0  = fma2(hl, w1[2 * k],     an0);
                an1  = fma2(hh, w1[2 * k + 1], an1);
            }
            v2f srz = arz0 + arz1;
            v2f sn  = an0 + an1;
            const float pre0 = srz.x + srz.y;   // r-pre (lanes<32) / z-pre (>=32)
            const float hn   = sn.x + sn.y;     // n hidden dot + b_hh

            const float sg    = fsig(pre0);
            const float other = __shfl_xor(sg, 32);
            const float rr = lo_half ? sg : other;
            const float zz = lo_half ? other : sg;

            const float nv = ftanh(fmaf(rr, hn, xn));   // n = tanh(xn + r*hn)
            h_el = fmaf(zz, h_el - nv, nv);             // h = n + z*(h-n)

            hout[i * 32] = h_el;      // both halves store identical bits: benign
            hsm[lane] = h_el;         // publish for next step (in-order DS pipe)
        }
        xv = xv_next;
    }
}

// out[t] = hbuf[t,:] . w_fc + b_fc
__global__ void fc_out(const float* __restrict__ hbuf,
                       const float* __restrict__ w_fc,
                       const float* __restrict__ b_fc,
                       float* __restrict__ out)
{
    const int t = blockIdx.x * blockDim.x + threadIdx.x;
    if (t >= TT) return;
    const float* h = hbuf + (size_t)t * 32;
    float acc = 0.f;
#pragma unroll
    for (int j = 0; j < 32; ++j) acc = fmaf(h[j], w_fc[j], acc);
    out[t] = acc + b_fc[0];
}

extern "C" void kernel_launch(void* const* d_in, const int* in_sizes, int n_in,
                              void* d_out, int out_size, void* d_ws, size_t ws_size,
                              hipStream_t stream) {
    const float* x    = (const float*)d_in[0];
    const float* w_ih = (const float*)d_in[1];
    const float* w_hh = (const float*)d_in[2];
    const float* b_ih = (const float*)d_in[3];
    const float* b_hh = (const float*)d_in[4];
    const float* w_fc = (const float*)d_in[5];
    const float* b_fc = (const float*)d_in[6];
    float* out  = (float*)d_out;
    float* hbuf = (float*)d_ws;   // TT*32*4 = 512 KB

    gru_seq<<<1, 64, 0, stream>>>(x, w_ih, w_hh, b_ih, b_hh, hbuf);
    fc_out<<<TT / 256, 256, 0, stream>>>(hbuf, w_fc, b_fc, out);
}

// Round 3
// 775.119 us; speedup vs baseline: 1.3013x; 1.1191x over previous
//
#include <hip/hip_runtime.h>

// GRU, T=4096, B=256, I=2, H=32, O=1.
// Only batch row 255 reaches the output -> compute only that row.
// Single-wave sequential recurrence; latency/issue-bound.
// R3: force 1 wave/EU so w_hh stays register-resident (R2 showed VGPR=64 ->
//     weights reloaded every step); fold exp2 scale factors into weights;
//     transposed hbuf with float4-batched stores.

#define TT 4096

typedef float v2f __attribute__((ext_vector_type(2)));

__device__ __forceinline__ v2f fma2(v2f a, v2f b, v2f c) {
    return __builtin_elementwise_fma(a, b, c);
}
__device__ __forceinline__ float rl(float v, int l) {
    return __int_as_float(__builtin_amdgcn_readlane(__float_as_int(v), l));
}
__device__ __forceinline__ float fexp2(float x) { return __builtin_amdgcn_exp2f(x); }
__device__ __forceinline__ float frcp(float x)  { return __builtin_amdgcn_rcpf(x); }

#define NLOG2E  (-1.44269504088896340736f)   // r/z dots pre-scaled by this
#define TLOG2E  ( 2.88539008177792681472f)   // n dot pre-scaled by this

// One wave. Lane l owns gate-row l of w_hh[0:64] (r rows on lanes 0..31,
// z rows on lanes 32..63) and n-row 64+(l&31) (duplicated across halves).
// h lives in LDS[0..63]; broadcast-read as 8x ds_read_b128 each step.
// One shfl_xor(32) swaps r<->z so both halves compute identical h bitwise.
__global__ __launch_bounds__(64, 1)
__attribute__((amdgpu_waves_per_eu(1, 1)))
void gru_seq(
    const float* __restrict__ x,
    const float* __restrict__ w_ih,
    const float* __restrict__ w_hh,
    const float* __restrict__ b_ih,
    const float* __restrict__ b_hh,
    float* __restrict__ hbuf)
{
    __shared__ float hsm[64];

    const int lane = threadIdx.x;
    const int low  = lane & 31;
    const int row0 = lane;        // r/z row
    const int row1 = 64 + low;    // n row (both halves)
    const bool lo_half = lane < 32;

    // w_hh rows as float2 pairs, pre-scaled so sigmoid/tanh need no mul:
    //   sigmoid(p) = rcp(1+exp2(-log2e * p))  -> accumulate p already * -log2e
    //   tanh(a)    = 1-2*rcp(1+exp2(2log2e*a))-> accumulate a already * 2log2e
    const v2f* w_hh2 = (const v2f*)w_hh;
    v2f w0[16], w1[16];
#pragma unroll
    for (int k = 0; k < 16; ++k) w0[k] = w_hh2[row0 * 16 + k] * NLOG2E;
#pragma unroll
    for (int k = 0; k < 16; ++k) w1[k] = w_hh2[row1 * 16 + k] * TLOG2E;

    const float wi00 = w_ih[row0 * 2 + 0] * NLOG2E;
    const float wi01 = w_ih[row0 * 2 + 1] * NLOG2E;
    const float wi10 = w_ih[row1 * 2 + 0] * TLOG2E;
    const float wi11 = w_ih[row1 * 2 + 1] * TLOG2E;
    const float bias0 = (b_ih[row0] + b_hh[row0]) * NLOG2E; // r/z: both biases
    const float bi1   = b_ih[row1] * TLOG2E;                // n: outside r*(...)
    const float bh1   = b_hh[row1] * TLOG2E;                // n: inside r*(...)

    hsm[lane] = 0.0f;          // single wave: DS pipe in-order, no barrier
    float h_el = 0.0f;         // each lane's copy of h[low]
    float hacc[4];             // 4-step store batch

    // x[t, 255, 0:2] as float2 at index t*256+255; 64 steps per lane-load,
    // prefetched one block ahead.
    const float2* xp = (const float2*)x;
    float2 xv = xp[(size_t)lane * 256 + 255];

    const float4* h4 = (const float4*)hsm;

    for (int tb = 0; tb < 64; ++tb) {
        float2 xv_next = xv;
        if (tb < 63) xv_next = xp[((size_t)(tb + 1) * 64 + lane) * 256 + 255];
        // transposed layout: hbuf[j*TT + t], t = tb*64 + i
        float4* hout = (float4*)(hbuf + (size_t)low * TT + tb * 64);

#pragma unroll 4
        for (int i = 0; i < 64; ++i) {
            const float x0 = rl(xv.x, i);
            const float x1 = rl(xv.y, i);
            const float base0 = fmaf(x1, wi01, fmaf(x0, wi00, bias0)); // scaled
            const float xn    = fmaf(x1, wi11, fmaf(x0, wi10, bi1));   // scaled

            // broadcast-read h: 8 x ds_read_b128, all lanes same address
            float4 hq[8];
#pragma unroll
            for (int k = 0; k < 8; ++k) hq[k] = h4[k];

            // packed dots: rz-row (per-lane) and n-row, 2 pk chains each
            v2f arz0 = {base0, 0.0f}, arz1 = {0.0f, 0.0f};
            v2f an0  = {bh1,   0.0f}, an1  = {0.0f, 0.0f};
#pragma unroll
            for (int k = 0; k < 8; ++k) {
                v2f hl = {hq[k].x, hq[k].y};
                v2f hh = {hq[k].z, hq[k].w};
                arz0 = fma2(hl, w0[2 * k],     arz0);
                arz1 = fma2(hh, w0[2 * k + 1], arz1);
                an0  = fma2(hl, w1[2 * k],     an0);
                an1  = fma2(hh, w1[2 * k + 1], an1);
            }
            v2f srz = arz0 + arz1;
            v2f sn  = an0 + an1;
            const float pre_s = srz.x + srz.y;  // -log2e * (r/z pre-act)
            const float hn_s  = sn.x + sn.y;    // 2log2e * (n hidden dot + b_hh)

            const float sg    = frcp(1.0f + fexp2(pre_s));  // sigmoid
            const float other = __shfl_xor(sg, 32);
            const float rr = lo_half ? sg : other;
            const float zz = lo_half ? other : sg;

            // n = tanh(xn + r*hn); arg pre-scaled by 2log2e
            const float nv = fmaf(-2.0f, frcp(1.0f + fexp2(fmaf(rr, hn_s, xn))), 1.0f);
            h_el = fmaf(zz, h_el - nv, nv);     // h = n + z*(h-n)

            hsm[lane] = h_el;                   // publish for next step
            hacc[i & 3] = h_el;
            if ((i & 3) == 3) hout[i >> 2] = *(const float4*)hacc;
        }
        xv = xv_next;
    }
}

// out[t] = sum_j hbuf[j*TT + t] * w_fc[j] + b_fc   (transposed hbuf)
__global__ void fc_out(const float* __restrict__ hbuf,
                       const float* __restrict__ w_fc,
                       const float* __restrict__ b_fc,
                       float* __restrict__ out)
{
    const int t = blockIdx.x * blockDim.x + threadIdx.x;
    if (t >= TT) return;
    float acc = 0.f;
#pragma unroll
    for (int j = 0; j < 32; ++j) acc = fmaf(hbuf[j * TT + t], w_fc[j], acc);
    out[t] = acc + b_fc[0];
}

extern "C" void kernel_launch(void* const* d_in, const int* in_sizes, int n_in,
                              void* d_out, int out_size, void* d_ws, size_t ws_size,
                              hipStream_t stream) {
    const float* x    = (const float*)d_in[0];
    const float* w_ih = (const float*)d_in[1];
    const float* w_hh = (const float*)d_in[2];
    const float* b_ih = (const float*)d_in[3];
    const float* b_hh = (const float*)d_in[4];
    const float* w_fc = (const float*)d_in[5];
    const float* b_fc = (const float*)d_in[6];
    float* out  = (float*)d_out;
    float* hbuf = (float*)d_ws;   // 32*TT*4 = 512 KB

    gru_seq<<<1, 64, 0, stream>>>(x, w_ih, w_hh, b_ih, b_hh, hbuf);
    fc_out<<<TT / 256, 256, 0, stream>>>(hbuf, w_fc, b_fc, out);
}